// Round 8
// baseline (517.894 us; speedup 1.0000x reference)
//
#include <hip/hip_runtime.h>
#include <math.h>
#include <stdint.h>

// ---------------------------------------------------------------------------
// DynamicBalancedMarginInnerProduct — R8 (R7 with LDS slot-stride fix).
//   1) norm_cvt4: row-norm + fp32->f16 cvt. nt LOADS (read-once fp32),
//      PLAIN stores (W16/A16 stay resident in L2/L3 for the GEMM).
//   2) gemm_cos_lds: 128x128 f16-MFMA tile, BK=32 (16KB LDS -> more
//      blocks/CU for TLP latency hiding), global_load_lds w16, XOR swizzle
//      kc ^ ((row>>1)&3) on source+read (2-way alias = free). Direct
//      register epilogue with PLAIN stores.
//      FIX vs R7: staging slot stride is 512 halfs (=1024 B per
//      global_load_lds slot), not 1024 halfs (was overflowing LDS -> NaN).
//   3) stats_fixup: deterministic reductions (vectorized norm_w scan).
// ---------------------------------------------------------------------------

typedef _Float16 f16x8 __attribute__((ext_vector_type(8)));
typedef float f32x4 __attribute__((ext_vector_type(4)));

#define SCALE_S 30.0f
#define RAD2DEG 57.29577951308232f
#define DEG2RAD 0.017453292519943295f

#define GL16(g, l)                                                    \
  __builtin_amdgcn_global_load_lds(                                   \
      (const __attribute__((address_space(1))) void*)(g),             \
      (__attribute__((address_space(3))) void*)(l), 16, 0, 0)

// --- fused row-norm + f16 convert, 1 wave per row --------------------------
__global__ __launch_bounds__(256) void norm_cvt4(
    const float* __restrict__ X, _Float16* __restrict__ X16, int K, int Cn,
    float* __restrict__ nrm, float* __restrict__ inv, int rows) {
  const int wid = threadIdx.x >> 6;
  const int lane = threadIdx.x & 63;
  const int row = blockIdx.x * 4 + wid;
  if (row >= rows) return;
  _Float16* o = X16 + (size_t)row * K;
  if (row >= Cn) {  // zero-pad rows
    for (int k = lane * 8; k < K; k += 512)
      *(f16x8*)(o + k) = (f16x8)(_Float16)0.f;
    return;
  }
  const float* r = X + (size_t)row * K;
  float s = 0.f;
  for (int k = lane * 8; k < K; k += 512) {
    f32x4 v0 = __builtin_nontemporal_load((const f32x4*)(r + k));
    f32x4 v1 = __builtin_nontemporal_load((const f32x4*)(r + k + 4));
    s += v0[0] * v0[0] + v0[1] * v0[1] + v0[2] * v0[2] + v0[3] * v0[3] +
         v1[0] * v1[0] + v1[1] * v1[1] + v1[2] * v1[2] + v1[3] * v1[3];
    f16x8 h;
    h[0] = (_Float16)v0[0]; h[1] = (_Float16)v0[1];
    h[2] = (_Float16)v0[2]; h[3] = (_Float16)v0[3];
    h[4] = (_Float16)v1[0]; h[5] = (_Float16)v1[1];
    h[6] = (_Float16)v1[2]; h[7] = (_Float16)v1[3];
    *(f16x8*)(o + k) = h;  // plain store: keep resident for the GEMM
  }
#pragma unroll
  for (int off = 32; off > 0; off >>= 1) s += __shfl_down(s, off);
  if (lane == 0) {
    float n = sqrtf(s);
    nrm[row] = n;
    inv[row] = 1.0f / n;
  }
}

__global__ __launch_bounds__(64) void row_norms_kernel(
    const float* __restrict__ X, int K,
    float* __restrict__ nrm, float* __restrict__ inv) {
  const int row = blockIdx.x;
  const float* r = X + (size_t)row * K;
  const int t = threadIdx.x;
  float s = 0.f;
  for (int k = t * 4; k < K; k += 64 * 4) {
    float4 v = *(const float4*)(r + k);
    s += v.x * v.x + v.y * v.y + v.z * v.z + v.w * v.w;
  }
#pragma unroll
  for (int off = 32; off > 0; off >>= 1) s += __shfl_down(s, off);
  if (t == 0) {
    float n = sqrtf(s);
    nrm[row] = n;
    inv[row] = 1.0f / n;
  }
}

// --- fast GEMM: f16 inputs, BK=32, global_load_lds, direct epilogue --------
// Tile image: 512 chunks of 8 halfs per array (4096 halfs = 8 KB each).
// Chunk c (c = slot*64 + lane, staged at halfs c*8) holds logical
// (row = c>>2, kchunk = (c&3) ^ ((row>>1)&3)). Reader fetches row r,
// kchunk kc at halfs r*32 + ((kc ^ ((r>>1)&3)) * 8) -> 2-way alias = free.
__global__ __launch_bounds__(256) void gemm_cos_lds(
    const _Float16* __restrict__ A16, const _Float16* __restrict__ W16,
    const float* __restrict__ inv_nf, const float* __restrict__ inv_nw,
    float* __restrict__ cosO, float* __restrict__ margO,
    int Cn, int npanel) {
  __shared__ __align__(16) _Float16 Ash[128 * 32];  // 8 KB
  __shared__ __align__(16) _Float16 Wsh[128 * 32];  // 8 KB
  const int K = 512;

  // XCD-bijective swizzle (nblk % 8 == 0), rows-fastest within XCD chunk
  const int nblk = npanel * 8;
  const int lin = blockIdx.x;
  const int q = nblk >> 3;
  const int wg = (lin & 7) * q + (lin >> 3);
  const int bm = (wg & 7) * 128;
  const int bn = (wg >> 3) * 128;

  const int t = threadIdx.x;
  const int lane = t & 63;
  const int w = t >> 6;
  const int wm = (w >> 1) * 64;
  const int wn = (w & 1) * 64;
  const int lrow = lane >> 4;   // 0..3 = kchunk for reads
  const int lcol = lane & 15;

  const _Float16* srcA[2];
  const _Float16* srcW[2];
#pragma unroll
  for (int i = 0; i < 2; ++i) {
    const int c = (w * 2 + i) * 64 + lane;   // chunk 0..511
    const int row = c >> 2;
    const int kcs = (c & 3) ^ ((row >> 1) & 3);
    srcA[i] = A16 + (size_t)(bm + row) * K + kcs * 8;
    srcW[i] = W16 + (size_t)(bn + row) * K + kcs * 8;
  }

  f32x4 acc[4][4];
#pragma unroll
  for (int m = 0; m < 4; ++m)
#pragma unroll
    for (int n = 0; n < 4; ++n) acc[m][n] = (f32x4)0.f;

  for (int s = 0; s < 16; ++s) {
    __syncthreads();  // prior LDS reads complete before DMA overwrite
#pragma unroll
    for (int i = 0; i < 2; ++i) {
      // slot stride = 512 halfs (64 lanes x 16 B per global_load_lds)
      GL16(srcA[i], Ash + (w * 2 + i) * 512);
      GL16(srcW[i], Wsh + (w * 2 + i) * 512);
      srcA[i] += 32;
      srcW[i] += 32;
    }
    __syncthreads();  // drains vmcnt -> staged tile visible

    f16x8 af[4], bf[4];
#pragma unroll
    for (int m = 0; m < 4; ++m) {
      const int rowa = wm + m * 16 + lcol;
      af[m] = *(const f16x8*)(Ash + rowa * 32 + ((lrow ^ ((rowa >> 1) & 3)) * 8));
      const int rowb = wn + m * 16 + lcol;
      bf[m] = *(const f16x8*)(Wsh + rowb * 32 + ((lrow ^ ((rowb >> 1) & 3)) * 8));
    }
#pragma unroll
    for (int m = 0; m < 4; ++m)
#pragma unroll
      for (int n = 0; n < 4; ++n)
        acc[m][n] = __builtin_amdgcn_mfma_f32_16x16x32_f16(
            af[m], bf[n], acc[m][n], 0, 0, 0);
  }

  // direct register epilogue (plain stores)
  float fi[4][4];
#pragma unroll
  for (int m = 0; m < 4; ++m)
#pragma unroll
    for (int r = 0; r < 4; ++r)
      fi[m][r] = inv_nf[bm + wm + m * 16 + lrow * 4 + r];

#pragma unroll
  for (int n = 0; n < 4; ++n) {
    const int col = bn + wn + n * 16 + lcol;
    if (col < Cn) {
      const float wiv = inv_nw[col];
#pragma unroll
      for (int m = 0; m < 4; ++m) {
        const int row0 = bm + wm + m * 16 + lrow * 4;
#pragma unroll
        for (int r = 0; r < 4; ++r) {
          const float v = acc[m][n][r] * fi[m][r] * wiv;
          const size_t o = (size_t)(row0 + r) * Cn + col;
          cosO[o] = v;
          margO[o] = SCALE_S * v;
        }
      }
    }
  }
}

// --- fallback GEMM (reg-staged from fp32, + XCD swizzle) -------------------
__global__ __launch_bounds__(256) void gemm_cos_f16(
    const float* __restrict__ A, const float* __restrict__ W,
    const float* __restrict__ inv_nf, const float* __restrict__ inv_nw,
    float* __restrict__ cosO, float* __restrict__ margO,
    int Cn, int K, int npanel) {
  __shared__ __align__(16) _Float16 Ash[128 * 64];
  __shared__ __align__(16) _Float16 Wsh[128 * 64];

  const int nblk = npanel * 8;
  const int lin = blockIdx.x;
  const int q = nblk >> 3;
  const int wg = (lin & 7) * q + (lin >> 3);
  const int bm = (wg & 7) * 128;
  const int bn = (wg >> 3) * 128;

  const int t = threadIdx.x;
  const int lane = t & 63;
  const int wid = t >> 6;
  const int wm = (wid >> 1) * 64;
  const int wn = (wid & 1) * 64;
  const int lrow = lane >> 4;
  const int lcol = lane & 15;

  int srow[4], skc[4];
#pragma unroll
  for (int j = 0; j < 4; ++j) {
    const int c = t + 256 * j;
    srow[j] = c >> 3;
    skc[j] = (t & 7) ^ (srow[j] & 7);
  }

  f32x4 acc[4][4];
#pragma unroll
  for (int m = 0; m < 4; ++m)
#pragma unroll
    for (int n = 0; n < 4; ++n) acc[m][n] = (f32x4)0.f;

  float4 ra[4][2], rw[4][2];
#pragma unroll
  for (int j = 0; j < 4; ++j) {
    const float* ap = A + (size_t)(bm + srow[j]) * K + skc[j] * 8;
    ra[j][0] = *(const float4*)ap;
    ra[j][1] = *(const float4*)(ap + 4);
    const int wr = bn + srow[j];
    if (wr < Cn) {
      const float* wp = W + (size_t)wr * K + skc[j] * 8;
      rw[j][0] = *(const float4*)wp;
      rw[j][1] = *(const float4*)(wp + 4);
    } else {
      rw[j][0] = make_float4(0.f, 0.f, 0.f, 0.f);
      rw[j][1] = make_float4(0.f, 0.f, 0.f, 0.f);
    }
  }

  const int nstep = K / 64;
  for (int s = 0; s < nstep; ++s) {
    __syncthreads();
#pragma unroll
    for (int j = 0; j < 4; ++j) {
      const int c = t + 256 * j;
      f16x8 ha, hw;
#pragma unroll
      for (int qq = 0; qq < 4; ++qq) {
        ha[qq] = (_Float16)((&ra[j][0].x)[qq]);
        ha[4 + qq] = (_Float16)((&ra[j][1].x)[qq]);
        hw[qq] = (_Float16)((&rw[j][0].x)[qq]);
        hw[4 + qq] = (_Float16)((&rw[j][1].x)[qq]);
      }
      *(f16x8*)(Ash + c * 8) = ha;
      *(f16x8*)(Wsh + c * 8) = hw;
    }
    __syncthreads();

    if (s + 1 < nstep) {
      const int k0 = (s + 1) * 64;
#pragma unroll
      for (int j = 0; j < 4; ++j) {
        const float* ap = A + (size_t)(bm + srow[j]) * K + k0 + skc[j] * 8;
        ra[j][0] = *(const float4*)ap;
        ra[j][1] = *(const float4*)(ap + 4);
        const int wr = bn + srow[j];
        if (wr < Cn) {
          const float* wp = W + (size_t)wr * K + k0 + skc[j] * 8;
          rw[j][0] = *(const float4*)wp;
          rw[j][1] = *(const float4*)(wp + 4);
        } else {
          rw[j][0] = make_float4(0.f, 0.f, 0.f, 0.f);
          rw[j][1] = make_float4(0.f, 0.f, 0.f, 0.f);
        }
      }
    }

#pragma unroll
    for (int ks = 0; ks < 2; ++ks) {
      f16x8 af[4], bf[4];
      const int kc = ks * 4 + lrow;
#pragma unroll
      for (int m = 0; m < 4; ++m) {
        const int rowa = wm + m * 16 + lcol;
        af[m] = *(const f16x8*)(Ash + rowa * 64 + ((kc ^ (rowa & 7)) * 8));
        const int rowb = wn + m * 16 + lcol;
        bf[m] = *(const f16x8*)(Wsh + rowb * 64 + ((kc ^ (rowb & 7)) * 8));
      }
#pragma unroll
      for (int m = 0; m < 4; ++m)
#pragma unroll
        for (int n = 0; n < 4; ++n)
          acc[m][n] = __builtin_amdgcn_mfma_f32_16x16x32_f16(
              af[m], bf[n], acc[m][n], 0, 0, 0);
    }
  }

  float fi[4][4];
#pragma unroll
  for (int m = 0; m < 4; ++m)
#pragma unroll
    for (int r = 0; r < 4; ++r)
      fi[m][r] = inv_nf[bm + wm + m * 16 + lrow * 4 + r];

#pragma unroll
  for (int n = 0; n < 4; ++n) {
    const int col = bn + wn + n * 16 + lcol;
    if (col < Cn) {
      const float wiv = inv_nw[col];
#pragma unroll
      for (int m = 0; m < 4; ++m) {
        const int row0 = bm + wm + m * 16 + lrow * 4;
#pragma unroll
        for (int r = 0; r < 4; ++r) {
          const float v = acc[m][n][r] * fi[m][r] * wiv;
          const size_t o = (size_t)(row0 + r) * Cn + col;
          cosO[o] = v;
          margO[o] = SCALE_S * v;
        }
      }
    }
  }
}

// --- stats + margin scatter ------------------------------------------------
__global__ __launch_bounds__(1024) void stats_fixup_kernel(
    const float* __restrict__ cosO, float* __restrict__ margO,
    const int* __restrict__ label,
    const float* __restrict__ norm_f, const float* __restrict__ norm_w,
    float* __restrict__ scal, int B, int Cn, int Wn) {
  __shared__ float red[1024];
  __shared__ float s_stat[4];
  const int t = threadIdx.x;

  const int lb = label[t];
  float tc = cosO[(size_t)t * Cn + lb];
  tc = fminf(1.0f, fmaxf(-1.0f, tc));
  const float theta = acosf(tc) * RAD2DEG;

  red[t] = theta; __syncthreads();
  for (int s = 512; s > 0; s >>= 1) {
    if (t < s) red[t] += red[t + s];
    __syncthreads();
  }
  if (t == 0) s_stat[2] = red[0] / (float)B;
  __syncthreads();
  const float avg = s_stat[2];
  __syncthreads();

  red[t] = theta; __syncthreads();
  for (int s = 512; s > 0; s >>= 1) {
    if (t < s) red[t] = fmaxf(red[t], red[t + s]);
    __syncthreads();
  }
  if (t == 0) s_stat[0] = red[0];
  __syncthreads();
  const float mx = s_stat[0];
  __syncthreads();

  red[t] = theta; __syncthreads();
  for (int s = 512; s > 0; s >>= 1) {
    if (t < s) red[t] = fminf(red[t], red[t + s]);
    __syncthreads();
  }
  if (t == 0) s_stat[1] = red[0];
  __syncthreads();
  const float mn = s_stat[1];
  __syncthreads();

  {
    const float d = theta - avg;
    red[t] = d * d;
  }
  __syncthreads();
  for (int s = 512; s > 0; s >>= 1) {
    if (t < s) red[t] += red[t + s];
    __syncthreads();
  }
  const float stdv = sqrtf(red[0] / (float)(B - 1));
  __syncthreads();

  const float margin_above = (mx < 90.0f) ? (90.0f - avg) * DEG2RAD : 0.0f;
  const float margin_below = mn * DEG2RAD;
  const float the_margin = (theta > avg) ? margin_above : margin_below;
  const bool in_range = tc > -cosf(the_margin);
  const float margin_add = in_range ? the_margin : 0.0f;
  const float margin_ext = in_range ? 0.0f : -the_margin * sinf(the_margin);
  const float tmarg = cosf(acosf(tc) + margin_add) + margin_ext;
  margO[(size_t)t * Cn + lb] = SCALE_S * tmarg;

  // avg_w_norm: vectorized scan (Wn % 4 == 0 fast path)
  float pw = 0.f;
  if ((Wn & 3) == 0) {
    for (int i = t * 4; i < Wn; i += 4096) {
      f32x4 v = *(const f32x4*)(norm_w + i);
      pw += v[0] + v[1] + v[2] + v[3];
    }
  } else {
    for (int i = t; i < Wn; i += 1024) pw += norm_w[i];
  }
  red[t] = pw; __syncthreads();
  for (int s = 512; s > 0; s >>= 1) {
    if (t < s) red[t] += red[t + s];
    __syncthreads();
  }
  const float avg_w = red[0] / (float)Wn;
  __syncthreads();

  red[t] = norm_f[t]; __syncthreads();
  for (int s = 512; s > 0; s >>= 1) {
    if (t < s) red[t] += red[t + s];
    __syncthreads();
  }
  const float avg_x = red[0] / (float)B;

  if (t == 0) {
    scal[0] = avg;
    scal[1] = mn;
    scal[2] = mx;
    scal[3] = stdv;
    scal[4] = avg_w;
    scal[5] = avg_x;
  }
}

extern "C" void kernel_launch(void* const* d_in, const int* in_sizes, int n_in,
                              void* d_out, int out_size, void* d_ws, size_t ws_size,
                              hipStream_t stream) {
  const float* feat = (const float*)d_in[0];
  const int* label = (const int*)d_in[1];
  const float* W = (const float*)d_in[2];

  const int B = in_sizes[1];            // 1024
  const int K = in_sizes[0] / B;        // 512
  const int Cn = in_sizes[2] / K;       // 100000
  const int CnPad = ((Cn + 127) / 128) * 128;  // 100096
  const int npanel = CnPad / 128;

  float* cosO = (float*)d_out;
  float* margO = cosO + (size_t)B * Cn;
  float* scal = margO + (size_t)B * Cn;

  float* norm_f = (float*)d_ws;
  float* inv_nf = norm_f + B;
  float* norm_w = inv_nf + B;
  float* inv_nw = norm_w + CnPad;
  _Float16* A16 = (_Float16*)(inv_nw + CnPad);
  _Float16* W16 = A16 + (size_t)B * K;

  const size_t need = sizeof(float) * (2 * (size_t)B + 2 * (size_t)CnPad) +
                      sizeof(_Float16) * ((size_t)B * K + (size_t)CnPad * K);

  if (ws_size >= need && (K % 512) == 0) {
    norm_cvt4<<<B / 4, 256, 0, stream>>>(feat, A16, K, B, norm_f, inv_nf, B);
    norm_cvt4<<<CnPad / 4, 256, 0, stream>>>(W, W16, K, Cn, norm_w, inv_nw,
                                             CnPad);
    gemm_cos_lds<<<npanel * 8, 256, 0, stream>>>(A16, W16, inv_nf, inv_nw,
                                                 cosO, margO, Cn, npanel);
  } else {
    row_norms_kernel<<<B, 64, 0, stream>>>(feat, K, norm_f, inv_nf);
    row_norms_kernel<<<Cn, 64, 0, stream>>>(W, K, norm_w, inv_nw);
    gemm_cos_f16<<<npanel * 8, 256, 0, stream>>>(feat, W, inv_nf, inv_nw,
                                                 cosO, margO, Cn, K, npanel);
  }

  stats_fixup_kernel<<<1, B, 0, stream>>>(cosO, margO, label, norm_f, norm_w,
                                          scal, B, Cn, Cn);
}

// Round 9
// 382.903 us; speedup vs baseline: 1.3525x; 1.3525x over previous
//
#include <hip/hip_runtime.h>
#include <math.h>
#include <stdint.h>

// ---------------------------------------------------------------------------
// DynamicBalancedMarginInnerProduct — R9 = R3 + ONE change:
//   gemm K-loop: BK=32 DOUBLE-BUFFERED (2x8KBx2 = 32KB LDS, same 4 blk/CU
//   as R3) with stage-early + single __syncthreads per iter, so the
//   compiler's vmcnt(0)-before-barrier drain lands AFTER the compute phase
//   (R3 drained immediately after issue -> full ~700cy exposed x8 steps).
//   Everything else is R3's proven config: norm_cvt prepass (plain stores),
//   nt direct epilogue, XOR-swizzled source+read (0 conflicts), XCD swizzle.
// ---------------------------------------------------------------------------

typedef _Float16 f16x8 __attribute__((ext_vector_type(8)));
typedef float f32x4 __attribute__((ext_vector_type(4)));

#define SCALE_S 30.0f
#define RAD2DEG 57.29577951308232f
#define DEG2RAD 0.017453292519943295f

#define GL16(g, l)                                                    \
  __builtin_amdgcn_global_load_lds(                                   \
      (const __attribute__((address_space(1))) void*)(g),             \
      (__attribute__((address_space(3))) void*)(l), 16, 0, 0)

// --- fused row-norm + f16 convert (R3's 64-thr/row version) ----------------
__global__ __launch_bounds__(64) void norm_cvt_kernel(
    const float* __restrict__ X, _Float16* __restrict__ X16, int K, int Cn,
    float* __restrict__ nrm, float* __restrict__ inv) {
  const int row = blockIdx.x;
  const int t = threadIdx.x;
  _Float16* o = X16 + (size_t)row * K;
  if (row >= Cn) {
    for (int k = t * 8; k < K; k += 64 * 8)
      *(f16x8*)(o + k) = (f16x8)(_Float16)0.f;
    return;
  }
  const float* r = X + (size_t)row * K;
  float s = 0.f;
  for (int k = t * 8; k < K; k += 64 * 8) {
    float4 v0 = *(const float4*)(r + k);
    float4 v1 = *(const float4*)(r + k + 4);
    s += v0.x * v0.x + v0.y * v0.y + v0.z * v0.z + v0.w * v0.w +
         v1.x * v1.x + v1.y * v1.y + v1.z * v1.z + v1.w * v1.w;
    f16x8 h;
    h[0] = (_Float16)v0.x; h[1] = (_Float16)v0.y;
    h[2] = (_Float16)v0.z; h[3] = (_Float16)v0.w;
    h[4] = (_Float16)v1.x; h[5] = (_Float16)v1.y;
    h[6] = (_Float16)v1.z; h[7] = (_Float16)v1.w;
    *(f16x8*)(o + k) = h;
  }
#pragma unroll
  for (int off = 32; off > 0; off >>= 1) s += __shfl_down(s, off);
  if (t == 0) {
    float n = sqrtf(s);
    nrm[row] = n;
    inv[row] = 1.0f / n;
  }
}

__global__ __launch_bounds__(64) void row_norms_kernel(
    const float* __restrict__ X, int K,
    float* __restrict__ nrm, float* __restrict__ inv) {
  const int row = blockIdx.x;
  const float* r = X + (size_t)row * K;
  const int t = threadIdx.x;
  float s = 0.f;
  for (int k = t * 4; k < K; k += 64 * 4) {
    float4 v = *(const float4*)(r + k);
    s += v.x * v.x + v.y * v.y + v.z * v.z + v.w * v.w;
  }
#pragma unroll
  for (int off = 32; off > 0; off >>= 1) s += __shfl_down(s, off);
  if (t == 0) {
    float n = sqrtf(s);
    nrm[row] = n;
    inv[row] = 1.0f / n;
  }
}

// --- fast GEMM: f16 inputs, BK=32 double-buffered global_load_lds ----------
// Per-tile image: 512 chunks of 8 halfs (chunk c at halfs c*8). Chunk c
// holds (row = c>>2, kchunk = (c&3) ^ ((row>>1)&3)); linear LDS dest
// (wave-uniform slot*512 + lane*8 implicit), per-lane permuted SOURCE;
// reader applies the same involution -> ~2-way bank alias only (free).
__global__ __launch_bounds__(256) void gemm_cos_lds(
    const _Float16* __restrict__ A16, const _Float16* __restrict__ W16,
    const float* __restrict__ inv_nf, const float* __restrict__ inv_nw,
    float* __restrict__ cosO, float* __restrict__ margO,
    int Cn, int npanel) {
  __shared__ __align__(16) _Float16 Ash[2][128 * 32];  // 2 x 8 KB
  __shared__ __align__(16) _Float16 Wsh[2][128 * 32];  // 2 x 8 KB
  const int K = 512;

  // XCD-bijective swizzle (nblk % 8 == 0), rows-fastest within XCD chunk
  const int nblk = npanel * 8;
  const int lin = blockIdx.x;
  const int q = nblk >> 3;
  const int wg = (lin & 7) * q + (lin >> 3);
  const int bm = (wg & 7) * 128;
  const int bn = (wg >> 3) * 128;

  const int t = threadIdx.x;
  const int lane = t & 63;
  const int w = t >> 6;
  const int wm = (w >> 1) * 64;
  const int wn = (w & 1) * 64;
  const int lrow = lane >> 4;   // 0..3 = kchunk for reads
  const int lcol = lane & 15;

  const _Float16* srcA[2];
  const _Float16* srcW[2];
#pragma unroll
  for (int i = 0; i < 2; ++i) {
    const int c = (w * 2 + i) * 64 + lane;   // chunk 0..511
    const int row = c >> 2;
    const int kcs = (c & 3) ^ ((row >> 1) & 3);
    srcA[i] = A16 + (size_t)(bm + row) * K + kcs * 8;
    srcW[i] = W16 + (size_t)(bn + row) * K + kcs * 8;
  }

  f32x4 acc[4][4];
#pragma unroll
  for (int m = 0; m < 4; ++m)
#pragma unroll
    for (int n = 0; n < 4; ++n) acc[m][n] = (f32x4)0.f;

  // prologue: stage K-tile 0 into buffer 0
#pragma unroll
  for (int i = 0; i < 2; ++i) {
    GL16(srcA[i], &Ash[0][(w * 2 + i) * 512]);
    GL16(srcW[i], &Wsh[0][(w * 2 + i) * 512]);
    srcA[i] += 32;
    srcW[i] += 32;
  }
  __syncthreads();  // tile 0 resident

  for (int s = 0; s < 16; ++s) {
    const int cur = s & 1;
    if (s < 15) {  // stage-early: issue tile s+1 into the idle buffer
#pragma unroll
      for (int i = 0; i < 2; ++i) {
        GL16(srcA[i], &Ash[cur ^ 1][(w * 2 + i) * 512]);
        GL16(srcW[i], &Wsh[cur ^ 1][(w * 2 + i) * 512]);
        srcA[i] += 32;
        srcW[i] += 32;
      }
    }
    // compute tile s from buf[cur]
    f16x8 af[4], bf[4];
#pragma unroll
    for (int m = 0; m < 4; ++m) {
      const int rowa = wm + m * 16 + lcol;
      af[m] = *(const f16x8*)(&Ash[cur][rowa * 32 + ((lrow ^ ((rowa >> 1) & 3)) * 8)]);
      const int rowb = wn + m * 16 + lcol;
      bf[m] = *(const f16x8*)(&Wsh[cur][rowb * 32 + ((lrow ^ ((rowb >> 1) & 3)) * 8)]);
    }
#pragma unroll
    for (int m = 0; m < 4; ++m)
#pragma unroll
      for (int n = 0; n < 4; ++n)
        acc[m][n] = __builtin_amdgcn_mfma_f32_16x16x32_f16(
            af[m], bf[n], acc[m][n], 0, 0, 0);
    // drain (tile s+1 loads have had the compute phase to progress) +
    // guard buf[cur] overwrite at iter s+1's stage
    __syncthreads();
  }

  // direct register epilogue (nt stores — R3's fastest variant)
  float fi[4][4];
#pragma unroll
  for (int m = 0; m < 4; ++m)
#pragma unroll
    for (int r = 0; r < 4; ++r)
      fi[m][r] = inv_nf[bm + wm + m * 16 + lrow * 4 + r];

#pragma unroll
  for (int n = 0; n < 4; ++n) {
    const int col = bn + wn + n * 16 + lcol;
    if (col < Cn) {
      const float wiv = inv_nw[col];
#pragma unroll
      for (int m = 0; m < 4; ++m) {
        const int row0 = bm + wm + m * 16 + lrow * 4;
#pragma unroll
        for (int r = 0; r < 4; ++r) {
          const float v = acc[m][n][r] * fi[m][r] * wiv;
          const size_t o = (size_t)(row0 + r) * Cn + col;
          __builtin_nontemporal_store(v, cosO + o);
          __builtin_nontemporal_store(SCALE_S * v, margO + o);
        }
      }
    }
  }
}

// --- fallback GEMM (reg-staged from fp32, + XCD swizzle) -------------------
__global__ __launch_bounds__(256) void gemm_cos_f16(
    const float* __restrict__ A, const float* __restrict__ W,
    const float* __restrict__ inv_nf, const float* __restrict__ inv_nw,
    float* __restrict__ cosO, float* __restrict__ margO,
    int Cn, int K, int npanel) {
  __shared__ __align__(16) _Float16 Ash[128 * 64];
  __shared__ __align__(16) _Float16 Wsh[128 * 64];

  const int nblk = npanel * 8;
  const int lin = blockIdx.x;
  const int q = nblk >> 3;
  const int wg = (lin & 7) * q + (lin >> 3);
  const int bm = (wg & 7) * 128;
  const int bn = (wg >> 3) * 128;

  const int t = threadIdx.x;
  const int lane = t & 63;
  const int wid = t >> 6;
  const int wm = (wid >> 1) * 64;
  const int wn = (wid & 1) * 64;
  const int lrow = lane >> 4;
  const int lcol = lane & 15;

  int srow[4], skc[4];
#pragma unroll
  for (int j = 0; j < 4; ++j) {
    const int c = t + 256 * j;
    srow[j] = c >> 3;
    skc[j] = (t & 7) ^ (srow[j] & 7);
  }

  f32x4 acc[4][4];
#pragma unroll
  for (int m = 0; m < 4; ++m)
#pragma unroll
    for (int n = 0; n < 4; ++n) acc[m][n] = (f32x4)0.f;

  float4 ra[4][2], rw[4][2];
#pragma unroll
  for (int j = 0; j < 4; ++j) {
    const float* ap = A + (size_t)(bm + srow[j]) * K + skc[j] * 8;
    ra[j][0] = *(const float4*)ap;
    ra[j][1] = *(const float4*)(ap + 4);
    const int wr = bn + srow[j];
    if (wr < Cn) {
      const float* wp = W + (size_t)wr * K + skc[j] * 8;
      rw[j][0] = *(const float4*)wp;
      rw[j][1] = *(const float4*)(wp + 4);
    } else {
      rw[j][0] = make_float4(0.f, 0.f, 0.f, 0.f);
      rw[j][1] = make_float4(0.f, 0.f, 0.f, 0.f);
    }
  }

  const int nstep = K / 64;
  for (int s = 0; s < nstep; ++s) {
    __syncthreads();
#pragma unroll
    for (int j = 0; j < 4; ++j) {
      const int c = t + 256 * j;
      f16x8 ha, hw;
#pragma unroll
      for (int qq = 0; qq < 4; ++qq) {
        ha[qq] = (_Float16)((&ra[j][0].x)[qq]);
        ha[4 + qq] = (_Float16)((&ra[j][1].x)[qq]);
        hw[qq] = (_Float16)((&rw[j][0].x)[qq]);
        hw[4 + qq] = (_Float16)((&rw[j][1].x)[qq]);
      }
      *(f16x8*)(Ash + c * 8) = ha;
      *(f16x8*)(Wsh + c * 8) = hw;
    }
    __syncthreads();

    if (s + 1 < nstep) {
      const int k0 = (s + 1) * 64;
#pragma unroll
      for (int j = 0; j < 4; ++j) {
        const float* ap = A + (size_t)(bm + srow[j]) * K + k0 + skc[j] * 8;
        ra[j][0] = *(const float4*)ap;
        ra[j][1] = *(const float4*)(ap + 4);
        const int wr = bn + srow[j];
        if (wr < Cn) {
          const float* wp = W + (size_t)wr * K + k0 + skc[j] * 8;
          rw[j][0] = *(const float4*)wp;
          rw[j][1] = *(const float4*)(wp + 4);
        } else {
          rw[j][0] = make_float4(0.f, 0.f, 0.f, 0.f);
          rw[j][1] = make_float4(0.f, 0.f, 0.f, 0.f);
        }
      }
    }

#pragma unroll
    for (int ks = 0; ks < 2; ++ks) {
      f16x8 af[4], bf[4];
      const int kc = ks * 4 + lrow;
#pragma unroll
      for (int m = 0; m < 4; ++m) {
        const int rowa = wm + m * 16 + lcol;
        af[m] = *(const f16x8*)(Ash + rowa * 64 + ((kc ^ (rowa & 7)) * 8));
        const int rowb = wn + m * 16 + lcol;
        bf[m] = *(const f16x8*)(Wsh + rowb * 64 + ((kc ^ (rowb & 7)) * 8));
      }
#pragma unroll
      for (int m = 0; m < 4; ++m)
#pragma unroll
        for (int n = 0; n < 4; ++n)
          acc[m][n] = __builtin_amdgcn_mfma_f32_16x16x32_f16(
              af[m], bf[n], acc[m][n], 0, 0, 0);
    }
  }

  float fi[4][4];
#pragma unroll
  for (int m = 0; m < 4; ++m)
#pragma unroll
    for (int r = 0; r < 4; ++r)
      fi[m][r] = inv_nf[bm + wm + m * 16 + lrow * 4 + r];

#pragma unroll
  for (int n = 0; n < 4; ++n) {
    const int col = bn + wn + n * 16 + lcol;
    if (col < Cn) {
      const float wiv = inv_nw[col];
#pragma unroll
      for (int m = 0; m < 4; ++m) {
        const int row0 = bm + wm + m * 16 + lrow * 4;
#pragma unroll
        for (int r = 0; r < 4; ++r) {
          const float v = acc[m][n][r] * fi[m][r] * wiv;
          const size_t o = (size_t)(row0 + r) * Cn + col;
          __builtin_nontemporal_store(v, cosO + o);
          __builtin_nontemporal_store(SCALE_S * v, margO + o);
        }
      }
    }
  }
}

// --- stats + margin scatter ------------------------------------------------
__global__ __launch_bounds__(1024) void stats_fixup_kernel(
    const float* __restrict__ cosO, float* __restrict__ margO,
    const int* __restrict__ label,
    const float* __restrict__ norm_f, const float* __restrict__ norm_w,
    float* __restrict__ scal, int B, int Cn, int Wn) {
  __shared__ float red[1024];
  __shared__ float s_stat[4];
  const int t = threadIdx.x;

  const int lb = label[t];
  float tc = cosO[(size_t)t * Cn + lb];
  tc = fminf(1.0f, fmaxf(-1.0f, tc));
  const float theta = acosf(tc) * RAD2DEG;

  red[t] = theta; __syncthreads();
  for (int s = 512; s > 0; s >>= 1) {
    if (t < s) red[t] += red[t + s];
    __syncthreads();
  }
  if (t == 0) s_stat[2] = red[0] / (float)B;
  __syncthreads();
  const float avg = s_stat[2];
  __syncthreads();

  red[t] = theta; __syncthreads();
  for (int s = 512; s > 0; s >>= 1) {
    if (t < s) red[t] = fmaxf(red[t], red[t + s]);
    __syncthreads();
  }
  if (t == 0) s_stat[0] = red[0];
  __syncthreads();
  const float mx = s_stat[0];
  __syncthreads();

  red[t] = theta; __syncthreads();
  for (int s = 512; s > 0; s >>= 1) {
    if (t < s) red[t] = fminf(red[t], red[t + s]);
    __syncthreads();
  }
  if (t == 0) s_stat[1] = red[0];
  __syncthreads();
  const float mn = s_stat[1];
  __syncthreads();

  {
    const float d = theta - avg;
    red[t] = d * d;
  }
  __syncthreads();
  for (int s = 512; s > 0; s >>= 1) {
    if (t < s) red[t] += red[t + s];
    __syncthreads();
  }
  const float stdv = sqrtf(red[0] / (float)(B - 1));
  __syncthreads();

  const float margin_above = (mx < 90.0f) ? (90.0f - avg) * DEG2RAD : 0.0f;
  const float margin_below = mn * DEG2RAD;
  const float the_margin = (theta > avg) ? margin_above : margin_below;
  const bool in_range = tc > -cosf(the_margin);
  const float margin_add = in_range ? the_margin : 0.0f;
  const float margin_ext = in_range ? 0.0f : -the_margin * sinf(the_margin);
  const float tmarg = cosf(acosf(tc) + margin_add) + margin_ext;
  margO[(size_t)t * Cn + lb] = SCALE_S * tmarg;

  float pw = 0.f;
  if ((Wn & 3) == 0) {
    for (int i = t * 4; i < Wn; i += 4096) {
      f32x4 v = *(const f32x4*)(norm_w + i);
      pw += v[0] + v[1] + v[2] + v[3];
    }
  } else {
    for (int i = t; i < Wn; i += 1024) pw += norm_w[i];
  }
  red[t] = pw; __syncthreads();
  for (int s = 512; s > 0; s >>= 1) {
    if (t < s) red[t] += red[t + s];
    __syncthreads();
  }
  const float avg_w = red[0] / (float)Wn;
  __syncthreads();

  red[t] = norm_f[t]; __syncthreads();
  for (int s = 512; s > 0; s >>= 1) {
    if (t < s) red[t] += red[t + s];
    __syncthreads();
  }
  const float avg_x = red[0] / (float)B;

  if (t == 0) {
    scal[0] = avg;
    scal[1] = mn;
    scal[2] = mx;
    scal[3] = stdv;
    scal[4] = avg_w;
    scal[5] = avg_x;
  }
}

extern "C" void kernel_launch(void* const* d_in, const int* in_sizes, int n_in,
                              void* d_out, int out_size, void* d_ws, size_t ws_size,
                              hipStream_t stream) {
  const float* feat = (const float*)d_in[0];
  const int* label = (const int*)d_in[1];
  const float* W = (const float*)d_in[2];

  const int B = in_sizes[1];            // 1024
  const int K = in_sizes[0] / B;        // 512
  const int Cn = in_sizes[2] / K;       // 100000
  const int CnPad = ((Cn + 127) / 128) * 128;  // 100096
  const int npanel = CnPad / 128;

  float* cosO = (float*)d_out;
  float* margO = cosO + (size_t)B * Cn;
  float* scal = margO + (size_t)B * Cn;

  float* norm_f = (float*)d_ws;
  float* inv_nf = norm_f + B;
  float* norm_w = inv_nf + B;
  float* inv_nw = norm_w + CnPad;
  _Float16* A16 = (_Float16*)(inv_nw + CnPad);
  _Float16* W16 = A16 + (size_t)B * K;

  const size_t need = sizeof(float) * (2 * (size_t)B + 2 * (size_t)CnPad) +
                      sizeof(_Float16) * ((size_t)B * K + (size_t)CnPad * K);

  if (ws_size >= need && (K % 512) == 0) {
    norm_cvt_kernel<<<B, 64, 0, stream>>>(feat, A16, K, B, norm_f, inv_nf);
    norm_cvt_kernel<<<CnPad, 64, 0, stream>>>(W, W16, K, Cn, norm_w, inv_nw);
    gemm_cos_lds<<<npanel * 8, 256, 0, stream>>>(A16, W16, inv_nf, inv_nw,
                                                 cosO, margO, Cn, npanel);
  } else {
    row_norms_kernel<<<B, 64, 0, stream>>>(feat, K, norm_f, inv_nf);
    row_norms_kernel<<<Cn, 64, 0, stream>>>(W, K, norm_w, inv_nw);
    gemm_cos_f16<<<npanel * 8, 256, 0, stream>>>(feat, W, inv_nf, inv_nw,
                                                 cosO, margO, Cn, K, npanel);
  }

  stats_fixup_kernel<<<1, B, 0, stream>>>(cosO, margO, label, norm_f, norm_w,
                                          scal, B, Cn, Cn);
}